// Round 6
// baseline (362.854 us; speedup 1.0000x reference)
//
#include <hip/hip_runtime.h>
#include <hip/hip_fp16.h>

// LightGCN 3-layer propagation, pull-based CSR, fp16 ego intermediates.
// Round 12: prep-chain pass (gather untouched at verified 75.8us/launch).
// Prep was 118us for ~90MB of traffic (~8x off roofline): 489-block
// hist/scatter (1.9 blocks/CU) with 8 serial scalar-load->LDS-atomic
// rounds per thread, and csr_finalize reading bpair twice.
//  (1) hist/scatter: 256-thr blocks, int4/float4 vectorized edge loads
//      (8 edges/thread up-front), 977 blocks.
//  (2) csr_finalize: stage the bucket run in LDS (<=5120 edges, +19sigma;
//      global fallback kept), single bpair read, sort out of LDS.
//  (3) zero_ints folded into lgcn_init (one fewer launch).

#define NUM_USERS 100000
#define NUM_ITEMS 50000
#define EMB_DIM   64
#define N_EDGES   2000000
#define N_NODES   (NUM_USERS + NUM_ITEMS)          // 150000
#define NODE_FLOATS (N_NODES * EMB_DIM)            // 9,600,000
#define NODE_F4     (NODE_FLOATS / 4)              // 2,400,000

#define NBUCKET  512
#define NPB      293        // nodes per bucket; 512*293 = 150016 >= 150000
#define NPART    8          // reservation partitions (XCD heuristic)
#define NCNT     (NBUCKET * NPART)                  // 4096

#define BT2      256        // threads in bucket passes
#define NE4      (N_EDGES / 4)                      // 500000 int4 groups
#define NT2      ((NE4 + 2 * BT2 - 1) / (2 * BT2)) // 977 blocks, 8 edges/thr

#define RUNCAP   5120       // LDS-staged bucket run capacity (mean 3906, +19s)

typedef unsigned int uint;
typedef unsigned short ushort;
typedef unsigned long long u64;

__device__ __forceinline__ float2 h2f2(uint u) {
    __half2 h = *reinterpret_cast<const __half2*>(&u);
    return __half22float2(h);
}
__device__ __forceinline__ uint f2h2(float a, float b) {
    __half2 h = __floats2half2_rn(a, b);
    return *reinterpret_cast<uint*>(&h);
}

// ---------- init: egoA(fp16) = concat(user,item); also zero bucketCount ----
__global__ void lgcn_init(const float4* __restrict__ user,
                          const float4* __restrict__ item,
                          uint2* __restrict__ egoA,
                          int* __restrict__ bucketCount) {
    const int n_user4 = NUM_USERS * EMB_DIM / 4;
    int gid = blockIdx.x * blockDim.x + threadIdx.x;
    if (gid < NCNT) bucketCount[gid] = 0;
    for (int i = gid; i < NODE_F4; i += gridDim.x * blockDim.x) {
        float4 v = (i < n_user4) ? user[i] : item[i - n_user4];
        egoA[i] = make_uint2(f2h2(v.x, v.y), f2h2(v.z, v.w));
    }
}

// ---------- pass A: histogram into (bucket, partition) counters ----------
__global__ __launch_bounds__(BT2) void bucket_hist(const int4* __restrict__ src4,
                                                   int* __restrict__ bucketCount) {
    __shared__ int cnt[NBUCKET];
    int t = threadIdx.x;
    int part = blockIdx.x & (NPART - 1);
    cnt[t] = 0;
    cnt[t + 256] = 0;
    __syncthreads();
    int i0 = blockIdx.x * (2 * BT2) + t;
    int i1 = i0 + BT2;
    if (i0 < NE4) {
        int4 s = src4[i0];
        atomicAdd(&cnt[s.x / NPB], 1);
        atomicAdd(&cnt[s.y / NPB], 1);
        atomicAdd(&cnt[s.z / NPB], 1);
        atomicAdd(&cnt[s.w / NPB], 1);
    }
    if (i1 < NE4) {
        int4 s = src4[i1];
        atomicAdd(&cnt[s.x / NPB], 1);
        atomicAdd(&cnt[s.y / NPB], 1);
        atomicAdd(&cnt[s.z / NPB], 1);
        atomicAdd(&cnt[s.w / NPB], 1);
    }
    __syncthreads();
    int c0 = cnt[t];
    int c1 = cnt[t + 256];
    if (c0) atomicAdd(&bucketCount[t * NPART + part], c0);
    if (c1) atomicAdd(&bucketCount[(t + 256) * NPART + part], c1);
}

// ---------- scan over 4096 (bucket,part) counters (1 block, 1024 thr) ----------
__global__ __launch_bounds__(1024) void bucket_scan(const int* __restrict__ bucketCount,
                                                    int* __restrict__ bucketOffset,
                                                    int* __restrict__ gCur,
                                                    int* __restrict__ rowPtr) {
    __shared__ int s[1024];
    int t = threadIdx.x;
    int4 c = *(const int4*)(bucketCount + t * 4);
    int sum = c.x + c.y + c.z + c.w;
    s[t] = sum;
    __syncthreads();
    for (int off = 1; off < 1024; off <<= 1) {
        int x = (t >= off) ? s[t - off] : 0;
        __syncthreads();
        s[t] += x;
        __syncthreads();
    }
    int base = s[t] - sum;   // exclusive
    int i0 = t * 4;
    bucketOffset[i0]     = base;
    bucketOffset[i0 + 1] = base + c.x;
    bucketOffset[i0 + 2] = base + c.x + c.y;
    bucketOffset[i0 + 3] = base + c.x + c.y + c.z;
    gCur[i0]     = base;
    gCur[i0 + 1] = base + c.x;
    gCur[i0 + 2] = base + c.x + c.y;
    gCur[i0 + 3] = base + c.x + c.y + c.z;
    if (t == 0) {
        bucketOffset[NCNT] = N_EDGES;
        rowPtr[N_NODES] = N_EDGES;
    }
}

// ---------- pass B: scatter packed edges into (bucket,part) runs ----------
// packed u64: [norm:32][src_local:9][dst:18]
__global__ __launch_bounds__(BT2) void bucket_scatter(const int4* __restrict__ src4,
                                                      const int4* __restrict__ dst4,
                                                      const float4* __restrict__ norm4,
                                                      int* __restrict__ gCur,
                                                      u64* __restrict__ bpair) {
    __shared__ int cnt[NBUCKET];
    __shared__ int bbase[NBUCKET];
    int t = threadIdx.x;
    int part = blockIdx.x & (NPART - 1);
    cnt[t] = 0;
    cnt[t + 256] = 0;
    __syncthreads();
    int i0 = blockIdx.x * (2 * BT2) + t;
    int i1 = i0 + BT2;
    bool va = i0 < NE4, vb = i1 < NE4;
    int4 sa, sb, da, db;
    float4 na, nb;
    if (va) {
        sa = src4[i0]; da = dst4[i0]; na = norm4[i0];
        atomicAdd(&cnt[sa.x / NPB], 1);
        atomicAdd(&cnt[sa.y / NPB], 1);
        atomicAdd(&cnt[sa.z / NPB], 1);
        atomicAdd(&cnt[sa.w / NPB], 1);
    }
    if (vb) {
        sb = src4[i1]; db = dst4[i1]; nb = norm4[i1];
        atomicAdd(&cnt[sb.x / NPB], 1);
        atomicAdd(&cnt[sb.y / NPB], 1);
        atomicAdd(&cnt[sb.z / NPB], 1);
        atomicAdd(&cnt[sb.w / NPB], 1);
    }
    __syncthreads();
    int c0 = cnt[t];
    int c1 = cnt[t + 256];
    bbase[t]       = c0 ? atomicAdd(&gCur[t * NPART + part], c0) : 0;
    bbase[t + 256] = c1 ? atomicAdd(&gCur[(t + 256) * NPART + part], c1) : 0;
    __syncthreads();
    cnt[t] = 0;
    cnt[t + 256] = 0;
    __syncthreads();

    #define EMIT(S, D, W) {                                             \
        int b_ = (S) / NPB;                                             \
        int sl_ = (S) - b_ * NPB;                                       \
        int r_ = atomicAdd(&cnt[b_], 1);                                \
        uint lo_ = (uint)(D) | ((uint)sl_ << 18);                       \
        bpair[bbase[b_] + r_] =                                         \
            (u64)lo_ | ((u64)(uint)__float_as_uint(W) << 32);           \
    }
    if (va) {
        EMIT(sa.x, da.x, na.x); EMIT(sa.y, da.y, na.y);
        EMIT(sa.z, da.z, na.z); EMIT(sa.w, da.w, na.w);
    }
    if (vb) {
        EMIT(sb.x, db.x, nb.x); EMIT(sb.y, db.y, nb.y);
        EMIT(sb.z, db.z, nb.z); EMIT(sb.w, db.w, nb.w);
    }
    #undef EMIT
}

// ---------- pass C: per-bucket CSR finalize (counting sort by src_local) ------
// Stages the bucket run in LDS (single bpair read); global fallback if the
// run exceeds RUNCAP (statistically never: mean 3906, std ~62).
__global__ __launch_bounds__(1024) void csr_finalize(const int* __restrict__ bucketOffset,
                                                     const u64* __restrict__ bpair,
                                                     int* __restrict__ rowPtr,
                                                     u64* __restrict__ pairs) {
    __shared__ int cnt[NBUCKET];
    __shared__ int cur[NBUCKET];
    __shared__ u64 run[RUNCAP];                     // 40 KB
    int b = blockIdx.x;
    int t = threadIdx.x;          // 1024 threads
    int beg = bucketOffset[b * NPART];
    int end = bucketOffset[b * NPART + NPART];
    int n = end - beg;
    int nodeBase = b * NPB;
    bool staged = (n <= RUNCAP);

    if (t < NBUCKET) cnt[t] = 0;
    __syncthreads();
    if (staged) {
        for (int i = t; i < n; i += 1024) {
            u64 p = bpair[beg + i];
            run[i] = p;
            atomicAdd(&cnt[((uint)p >> 18) & 0x1FF], 1);
        }
    } else {
        for (int i = beg + t; i < end; i += 1024) {
            uint lo = (uint)bpair[i];
            atomicAdd(&cnt[(lo >> 18) & 0x1FF], 1);
        }
    }
    __syncthreads();
    int v = (t < NBUCKET) ? cnt[t] : 0;
    for (int off = 1; off < NBUCKET; off <<= 1) {     // inclusive scan, 512-wide
        int x = (t >= off && t < NBUCKET) ? cnt[t - off] : 0;
        __syncthreads();
        if (t < NBUCKET) cnt[t] += x;
        __syncthreads();
    }
    if (t < NBUCKET) {
        int excl = cnt[t] - v;
        cur[t] = excl;
        int node = nodeBase + t;
        if (t < NPB && node < N_NODES) rowPtr[node] = beg + excl;
    }
    __syncthreads();
    if (staged) {
        for (int i = t; i < n; i += 1024) {
            u64 p = run[i];
            int s = ((uint)p >> 18) & 0x1FF;
            int r = atomicAdd(&cur[s], 1);
            pairs[beg + r] = p;
        }
    } else {
        for (int i = beg + t; i < end; i += 1024) {
            u64 p = bpair[i];
            int s = ((uint)p >> 18) & 0x1FF;
            int r = atomicAdd(&cur[s], 1);
            pairs[beg + r] = p;
        }
    }
}

// ---------- gather: 2 nodes/wave, 4 lane-groups of 8 per node ----------
// finalMode==0: nego = fp16(s)                    (no acc access)
// finalMode==1: acc  = (e0 + e1 + ego + s) * 0.25 (no nego write)
__global__ void lgcn_gather(const ushort* __restrict__ ego,
                            ushort* __restrict__ nego,
                            float* __restrict__ acc,
                            const ushort* __restrict__ e0,
                            const ushort* __restrict__ e1,
                            const int* __restrict__ rowPtr,
                            const u64* __restrict__ pairs,
                            int finalMode) {
    // 256 threads = 4 waves = 8 nodes (one node per 32-lane half-wave)
    int node   = blockIdx.x * 8 + (threadIdx.x >> 5);
    int lane32 = threadIdx.x & 31;
    int g      = lane32 >> 3;       // 4 edge streams per node
    int sub    = lane32 & 7;        // uint4 position within the 128B row
    if (node >= N_NODES) return;
    int beg = rowPtr[node];
    int end = rowPtr[node + 1];

    float s0 = 0.f, s1 = 0.f, s2 = 0.f, s3 = 0.f;
    float s4 = 0.f, s5 = 0.f, s6 = 0.f, s7 = 0.f;
    for (int i = beg + g; i < end; i += 4) {
        u64 p = pairs[i];                       // cached: re-read by layers 2/3
        uint lo = (uint)p;
        float w = __uint_as_float((uint)(p >> 32));
        int d = lo & 0x3FFFF;
        uint4 r = *(const uint4*)(ego + ((size_t)d << 6) + (sub << 3));
        float2 q;
        q = h2f2(r.x); s0 += w * q.x; s1 += w * q.y;
        q = h2f2(r.y); s2 += w * q.x; s3 += w * q.y;
        q = h2f2(r.z); s4 += w * q.x; s5 += w * q.y;
        q = h2f2(r.w); s6 += w * q.x; s7 += w * q.y;
    }

    // reduce 4 streams -> lanes (lane32 < 8) of each half-wave.
    s0 += __shfl_down(s0, 16); s1 += __shfl_down(s1, 16);
    s2 += __shfl_down(s2, 16); s3 += __shfl_down(s3, 16);
    s4 += __shfl_down(s4, 16); s5 += __shfl_down(s5, 16);
    s6 += __shfl_down(s6, 16); s7 += __shfl_down(s7, 16);
    s0 += __shfl_down(s0, 8);  s1 += __shfl_down(s1, 8);
    s2 += __shfl_down(s2, 8);  s3 += __shfl_down(s3, 8);
    s4 += __shfl_down(s4, 8);  s5 += __shfl_down(s5, 8);
    s6 += __shfl_down(s6, 8);  s7 += __shfl_down(s7, 8);

    if (lane32 < 8) {
        size_t ro = ((size_t)node << 6) + (lane32 << 3);   // dims lane32*8..+7
        if (!finalMode) {
            uint4* np = (uint4*)(nego + ro);
            *np = make_uint4(f2h2(s0, s1), f2h2(s2, s3),
                             f2h2(s4, s5), f2h2(s6, s7));
        } else {
            uint4 z0 = *(const uint4*)(e0  + ro);
            uint4 z1 = *(const uint4*)(e1  + ro);
            uint4 z2 = *(const uint4*)(ego + ro);
            float2 a, b, c;
            float4 o0, o1;
            a = h2f2(z0.x); b = h2f2(z1.x); c = h2f2(z2.x);
            o0.x = (a.x + b.x + c.x + s0) * 0.25f;
            o0.y = (a.y + b.y + c.y + s1) * 0.25f;
            a = h2f2(z0.y); b = h2f2(z1.y); c = h2f2(z2.y);
            o0.z = (a.x + b.x + c.x + s2) * 0.25f;
            o0.w = (a.y + b.y + c.y + s3) * 0.25f;
            a = h2f2(z0.z); b = h2f2(z1.z); c = h2f2(z2.z);
            o1.x = (a.x + b.x + c.x + s4) * 0.25f;
            o1.y = (a.y + b.y + c.y + s5) * 0.25f;
            a = h2f2(z0.w); b = h2f2(z1.w); c = h2f2(z2.w);
            o1.z = (a.x + b.x + c.x + s6) * 0.25f;
            o1.w = (a.y + b.y + c.y + s7) * 0.25f;
            float4* ap = (float4*)(acc + ro);
            ap[0] = o0;
            ap[1] = o1;
        }
    }
}

extern "C" void kernel_launch(void* const* d_in, const int* in_sizes, int n_in,
                              void* d_out, int out_size, void* d_ws, size_t ws_size,
                              hipStream_t stream) {
    const float* user_emb  = (const float*)d_in[0];
    const float* item_emb  = (const float*)d_in[1];
    const float* edge_norm = (const float*)d_in[2];
    const int*   edge_src  = (const int*)d_in[3];
    const int*   edge_dst  = (const int*)d_in[4];
    float* acc = (float*)d_out;

    char* w = (char*)d_ws;
    ushort* egoA  = (ushort*)w;                      w += (size_t)NODE_FLOATS * 2;   // 19.2 MB
    ushort* egoB  = (ushort*)w;                      w += (size_t)NODE_FLOATS * 2;   // 19.2 MB
    u64*   pairs  = (u64*)w;                         w += (size_t)N_EDGES * 8;       // 16 MB
    int*   rowPtr = (int*)w;                         w += (size_t)(N_NODES + 4) * 4;
    int*   bucketCount  = (int*)w;                   w += (size_t)NCNT * 4;
    int*   bucketOffset = (int*)w;                   w += (size_t)(NCNT + 4) * 4;
    int*   gCur   = (int*)w;                         w += (size_t)NCNT * 4;
    // bpair (16 MB, dead after csr_finalize) and egoC (19.2 MB, born at
    // layer-2 gather) share the tail region: lifetimes don't overlap.
    u64*   bpair  = (u64*)w;
    ushort* egoC  = (ushort*)w;

    const int T = 256;
    const int EW_BLOCKS = 2048;
    const int GATHER_BLOCKS = (N_NODES + 7) / 8;     // 18750

    lgcn_init<<<EW_BLOCKS, T, 0, stream>>>(
        (const float4*)user_emb, (const float4*)item_emb, (uint2*)egoA,
        bucketCount);

    bucket_hist<<<NT2, BT2, 0, stream>>>((const int4*)edge_src, bucketCount);
    bucket_scan<<<1, 1024, 0, stream>>>(bucketCount, bucketOffset, gCur, rowPtr);
    bucket_scatter<<<NT2, BT2, 0, stream>>>((const int4*)edge_src,
                                            (const int4*)edge_dst,
                                            (const float4*)edge_norm,
                                            gCur, bpair);
    csr_finalize<<<NBUCKET, 1024, 0, stream>>>(bucketOffset, bpair,
                                               rowPtr, pairs);

    // Layer 1: ego0(A) -> ego1(B)             (nego only)
    lgcn_gather<<<GATHER_BLOCKS, T, 0, stream>>>(egoA, egoB, acc,
                                                 (const ushort*)0, (const ushort*)0,
                                                 rowPtr, pairs, 0);
    // Layer 2: ego1(B) -> ego2(C)             (nego only)
    lgcn_gather<<<GATHER_BLOCKS, T, 0, stream>>>(egoB, egoC, acc,
                                                 (const ushort*)0, (const ushort*)0,
                                                 rowPtr, pairs, 0);
    // Layer 3: ego2(C) -> s; acc = (A + B + C + s) / 4
    lgcn_gather<<<GATHER_BLOCKS, T, 0, stream>>>(egoC, (ushort*)0, acc,
                                                 egoA, egoB,
                                                 rowPtr, pairs, 1);
}

// Round 7
// 334.428 us; speedup vs baseline: 1.0850x; 1.0850x over previous
//
#include <hip/hip_runtime.h>
#include <hip/hip_fp16.h>

// LightGCN 3-layer propagation, pull-based CSR, fp16 ego intermediates.
// Round 13: prep REVERTED verbatim to the verified round-11 chain (round-12's
// LDS-staged finalize + 256-thr vectorized hist/scatter regressed prep
// 118->136us: the second bpair pass it "saved" was an L2 hit, and the LDS
// staging added real work). One experiment this round, in the gather:
// 2x manual unroll of each edge stream (pairs[i] & pairs[i+4] issued
// together, both ego rows in flight, dual accumulator banks) -> ~16
// outstanding row loads/wave instead of ~8. MLP was the limiter (BW rose
// 2.35->3.82 TB/s when MLP rose; VALU 27%, occ 75%: nothing else is).

#define NUM_USERS 100000
#define NUM_ITEMS 50000
#define EMB_DIM   64
#define N_EDGES   2000000
#define N_NODES   (NUM_USERS + NUM_ITEMS)          // 150000
#define NODE_FLOATS (N_NODES * EMB_DIM)            // 9,600,000
#define NODE_F4     (NODE_FLOATS / 4)              // 2,400,000

#define NBUCKET  512
#define NPB      293        // nodes per bucket; 512*293 = 150016 >= 150000
#define NPART    8          // reservation partitions (XCD heuristic)
#define NCNT     (NBUCKET * NPART)                  // 4096
#define BT       512        // threads in bucket passes
#define VPT      8          // edges per thread in bucket passes
#define TILE     (BT * VPT)                         // 4096
#define NTILE    ((N_EDGES + TILE - 1) / TILE)      // 489

typedef unsigned int uint;
typedef unsigned short ushort;
typedef unsigned long long u64;

__device__ __forceinline__ float2 h2f2(uint u) {
    __half2 h = *reinterpret_cast<const __half2*>(&u);
    return __half22float2(h);
}
__device__ __forceinline__ uint f2h2(float a, float b) {
    __half2 h = __floats2half2_rn(a, b);
    return *reinterpret_cast<uint*>(&h);
}

// ---------- init: egoA(fp16) = concat(user,item) ----------
__global__ void lgcn_init(const float4* __restrict__ user,
                          const float4* __restrict__ item,
                          uint2* __restrict__ egoA) {
    const int n_user4 = NUM_USERS * EMB_DIM / 4;
    for (int i = blockIdx.x * blockDim.x + threadIdx.x; i < NODE_F4;
         i += gridDim.x * blockDim.x) {
        float4 v = (i < n_user4) ? user[i] : item[i - n_user4];
        egoA[i] = make_uint2(f2h2(v.x, v.y), f2h2(v.z, v.w));
    }
}

__global__ void zero_ints(int* __restrict__ p, int n) {
    int i = blockIdx.x * blockDim.x + threadIdx.x;
    if (i < n) p[i] = 0;
}

// ---------- pass A: histogram into (bucket, partition) counters ----------
__global__ __launch_bounds__(BT) void bucket_hist(const int* __restrict__ src,
                                                  int* __restrict__ bucketCount) {
    __shared__ int cnt[NBUCKET];
    int t = threadIdx.x;
    int part = blockIdx.x & (NPART - 1);
    cnt[t] = 0;
    __syncthreads();
    int base = blockIdx.x * TILE + t;
    #pragma unroll
    for (int k = 0; k < VPT; ++k) {
        int e = base + k * BT;
        if (e < N_EDGES) atomicAdd(&cnt[src[e] / NPB], 1);
    }
    __syncthreads();
    int c = cnt[t];
    if (c) atomicAdd(&bucketCount[t * NPART + part], c);
}

// ---------- scan over 4096 (bucket,part) counters (1 block, 1024 thr) ----------
__global__ __launch_bounds__(1024) void bucket_scan(const int* __restrict__ bucketCount,
                                                    int* __restrict__ bucketOffset,
                                                    int* __restrict__ gCur,
                                                    int* __restrict__ rowPtr) {
    __shared__ int s[1024];
    int t = threadIdx.x;
    int4 c = *(const int4*)(bucketCount + t * 4);
    int sum = c.x + c.y + c.z + c.w;
    s[t] = sum;
    __syncthreads();
    for (int off = 1; off < 1024; off <<= 1) {
        int x = (t >= off) ? s[t - off] : 0;
        __syncthreads();
        s[t] += x;
        __syncthreads();
    }
    int base = s[t] - sum;   // exclusive
    int i0 = t * 4;
    bucketOffset[i0]     = base;
    bucketOffset[i0 + 1] = base + c.x;
    bucketOffset[i0 + 2] = base + c.x + c.y;
    bucketOffset[i0 + 3] = base + c.x + c.y + c.z;
    gCur[i0]     = base;
    gCur[i0 + 1] = base + c.x;
    gCur[i0 + 2] = base + c.x + c.y;
    gCur[i0 + 3] = base + c.x + c.y + c.z;
    if (t == 0) {
        bucketOffset[NCNT] = N_EDGES;
        rowPtr[N_NODES] = N_EDGES;
    }
}

// ---------- pass B: scatter packed edges into (bucket,part) runs ----------
// packed u64: [norm:32][src_local:9][dst:18]
__global__ __launch_bounds__(BT) void bucket_scatter(const int* __restrict__ src,
                                                     const int* __restrict__ dst,
                                                     const float* __restrict__ norm,
                                                     int* __restrict__ gCur,
                                                     u64* __restrict__ bpair) {
    __shared__ int cnt[NBUCKET];
    __shared__ int bbase[NBUCKET];
    int t = threadIdx.x;
    int part = blockIdx.x & (NPART - 1);
    cnt[t] = 0;
    __syncthreads();
    int base = blockIdx.x * TILE + t;
    #pragma unroll
    for (int k = 0; k < VPT; ++k) {
        int e = base + k * BT;
        if (e < N_EDGES) atomicAdd(&cnt[src[e] / NPB], 1);
    }
    __syncthreads();
    int c = cnt[t];
    bbase[t] = c ? atomicAdd(&gCur[t * NPART + part], c) : 0;
    __syncthreads();
    cnt[t] = 0;
    __syncthreads();
    #pragma unroll
    for (int k = 0; k < VPT; ++k) {
        int e = base + k * BT;
        if (e < N_EDGES) {
            int s = src[e];
            int b = s / NPB;
            int sl = s - b * NPB;                    // 0..292
            int r = atomicAdd(&cnt[b], 1);
            uint lo = (uint)dst[e] | ((uint)sl << 18);
            u64 packed = (u64)lo | ((u64)(uint)__float_as_uint(norm[e]) << 32);
            bpair[bbase[b] + r] = packed;
        }
    }
}

// ---------- pass C: per-bucket CSR finalize (counting sort by src_local) ----------
__global__ __launch_bounds__(1024) void csr_finalize(const int* __restrict__ bucketOffset,
                                                     const u64* __restrict__ bpair,
                                                     int* __restrict__ rowPtr,
                                                     u64* __restrict__ pairs) {
    __shared__ int cnt[NBUCKET];
    __shared__ int cur[NBUCKET];
    int b = blockIdx.x;
    int t = threadIdx.x;          // 1024 threads
    int beg = bucketOffset[b * NPART];
    int end = bucketOffset[b * NPART + NPART];
    int nodeBase = b * NPB;

    if (t < NBUCKET) cnt[t] = 0;
    __syncthreads();
    for (int i = beg + t; i < end; i += 1024) {
        uint lo = (uint)bpair[i];
        atomicAdd(&cnt[(lo >> 18) & 0x1FF], 1);
    }
    __syncthreads();
    int v = (t < NBUCKET) ? cnt[t] : 0;
    for (int off = 1; off < NBUCKET; off <<= 1) {     // inclusive scan, 512-wide
        int x = (t >= off && t < NBUCKET) ? cnt[t - off] : 0;
        __syncthreads();
        if (t < NBUCKET) cnt[t] += x;
        __syncthreads();
    }
    if (t < NBUCKET) {
        int excl = cnt[t] - v;
        cur[t] = excl;
        int node = nodeBase + t;
        if (t < NPB && node < N_NODES) rowPtr[node] = beg + excl;
    }
    __syncthreads();
    for (int i = beg + t; i < end; i += 1024) {
        u64 p = bpair[i];
        int s = ((uint)p >> 18) & 0x1FF;
        int r = atomicAdd(&cur[s], 1);
        pairs[beg + r] = p;
    }
}

// ---------- gather: 2 nodes/wave, 4 streams x 2-deep unroll per node ----------
// finalMode==0: nego = fp16(s)                    (no acc access)
// finalMode==1: acc  = (e0 + e1 + ego + s) * 0.25 (no nego write)
__global__ void lgcn_gather(const ushort* __restrict__ ego,
                            ushort* __restrict__ nego,
                            float* __restrict__ acc,
                            const ushort* __restrict__ e0,
                            const ushort* __restrict__ e1,
                            const int* __restrict__ rowPtr,
                            const u64* __restrict__ pairs,
                            int finalMode) {
    // 256 threads = 4 waves = 8 nodes (one node per 32-lane half-wave)
    int node   = blockIdx.x * 8 + (threadIdx.x >> 5);
    int lane32 = threadIdx.x & 31;
    int g      = lane32 >> 3;       // 4 edge streams per node
    int sub    = lane32 & 7;        // uint4 position within the 128B row
    if (node >= N_NODES) return;
    int beg = rowPtr[node];
    int end = rowPtr[node + 1];

    // bank A and bank B accumulators (merged after the loop) break the
    // FMA dependency chain so both row loads stay in flight.
    float a0 = 0.f, a1 = 0.f, a2 = 0.f, a3 = 0.f;
    float a4 = 0.f, a5 = 0.f, a6 = 0.f, a7 = 0.f;
    float b0 = 0.f, b1 = 0.f, b2 = 0.f, b3 = 0.f;
    float b4 = 0.f, b5 = 0.f, b6 = 0.f, b7 = 0.f;

    int i = beg + g;
    for (; i + 4 < end; i += 8) {
        u64 pA = pairs[i];
        u64 pB = pairs[i + 4];
        uint loA = (uint)pA, loB = (uint)pB;
        float wA = __uint_as_float((uint)(pA >> 32));
        float wB = __uint_as_float((uint)(pB >> 32));
        uint4 rA = *(const uint4*)(ego + ((size_t)(loA & 0x3FFFF) << 6) + (sub << 3));
        uint4 rB = *(const uint4*)(ego + ((size_t)(loB & 0x3FFFF) << 6) + (sub << 3));
        float2 q;
        q = h2f2(rA.x); a0 += wA * q.x; a1 += wA * q.y;
        q = h2f2(rA.y); a2 += wA * q.x; a3 += wA * q.y;
        q = h2f2(rA.z); a4 += wA * q.x; a5 += wA * q.y;
        q = h2f2(rA.w); a6 += wA * q.x; a7 += wA * q.y;
        q = h2f2(rB.x); b0 += wB * q.x; b1 += wB * q.y;
        q = h2f2(rB.y); b2 += wB * q.x; b3 += wB * q.y;
        q = h2f2(rB.z); b4 += wB * q.x; b5 += wB * q.y;
        q = h2f2(rB.w); b6 += wB * q.x; b7 += wB * q.y;
    }
    if (i < end) {
        u64 p = pairs[i];
        uint lo = (uint)p;
        float w = __uint_as_float((uint)(p >> 32));
        uint4 r = *(const uint4*)(ego + ((size_t)(lo & 0x3FFFF) << 6) + (sub << 3));
        float2 q;
        q = h2f2(r.x); a0 += w * q.x; a1 += w * q.y;
        q = h2f2(r.y); a2 += w * q.x; a3 += w * q.y;
        q = h2f2(r.z); a4 += w * q.x; a5 += w * q.y;
        q = h2f2(r.w); a6 += w * q.x; a7 += w * q.y;
    }
    float s0 = a0 + b0, s1 = a1 + b1, s2 = a2 + b2, s3 = a3 + b3;
    float s4 = a4 + b4, s5 = a5 + b5, s6 = a6 + b6, s7 = a7 + b7;

    // reduce 4 streams -> lanes (lane32 < 8) of each half-wave.
    s0 += __shfl_down(s0, 16); s1 += __shfl_down(s1, 16);
    s2 += __shfl_down(s2, 16); s3 += __shfl_down(s3, 16);
    s4 += __shfl_down(s4, 16); s5 += __shfl_down(s5, 16);
    s6 += __shfl_down(s6, 16); s7 += __shfl_down(s7, 16);
    s0 += __shfl_down(s0, 8);  s1 += __shfl_down(s1, 8);
    s2 += __shfl_down(s2, 8);  s3 += __shfl_down(s3, 8);
    s4 += __shfl_down(s4, 8);  s5 += __shfl_down(s5, 8);
    s6 += __shfl_down(s6, 8);  s7 += __shfl_down(s7, 8);

    if (lane32 < 8) {
        size_t ro = ((size_t)node << 6) + (lane32 << 3);   // dims lane32*8..+7
        if (!finalMode) {
            uint4* np = (uint4*)(nego + ro);
            *np = make_uint4(f2h2(s0, s1), f2h2(s2, s3),
                             f2h2(s4, s5), f2h2(s6, s7));
        } else {
            uint4 z0 = *(const uint4*)(e0  + ro);
            uint4 z1 = *(const uint4*)(e1  + ro);
            uint4 z2 = *(const uint4*)(ego + ro);
            float2 a, b, c;
            float4 o0, o1;
            a = h2f2(z0.x); b = h2f2(z1.x); c = h2f2(z2.x);
            o0.x = (a.x + b.x + c.x + s0) * 0.25f;
            o0.y = (a.y + b.y + c.y + s1) * 0.25f;
            a = h2f2(z0.y); b = h2f2(z1.y); c = h2f2(z2.y);
            o0.z = (a.x + b.x + c.x + s2) * 0.25f;
            o0.w = (a.y + b.y + c.y + s3) * 0.25f;
            a = h2f2(z0.z); b = h2f2(z1.z); c = h2f2(z2.z);
            o1.x = (a.x + b.x + c.x + s4) * 0.25f;
            o1.y = (a.y + b.y + c.y + s5) * 0.25f;
            a = h2f2(z0.w); b = h2f2(z1.w); c = h2f2(z2.w);
            o1.z = (a.x + b.x + c.x + s6) * 0.25f;
            o1.w = (a.y + b.y + c.y + s7) * 0.25f;
            float4* ap = (float4*)(acc + ro);
            ap[0] = o0;
            ap[1] = o1;
        }
    }
}

extern "C" void kernel_launch(void* const* d_in, const int* in_sizes, int n_in,
                              void* d_out, int out_size, void* d_ws, size_t ws_size,
                              hipStream_t stream) {
    const float* user_emb  = (const float*)d_in[0];
    const float* item_emb  = (const float*)d_in[1];
    const float* edge_norm = (const float*)d_in[2];
    const int*   edge_src  = (const int*)d_in[3];
    const int*   edge_dst  = (const int*)d_in[4];
    float* acc = (float*)d_out;

    char* w = (char*)d_ws;
    ushort* egoA  = (ushort*)w;                      w += (size_t)NODE_FLOATS * 2;   // 19.2 MB
    ushort* egoB  = (ushort*)w;                      w += (size_t)NODE_FLOATS * 2;   // 19.2 MB
    u64*   pairs  = (u64*)w;                         w += (size_t)N_EDGES * 8;       // 16 MB
    int*   rowPtr = (int*)w;                         w += (size_t)(N_NODES + 4) * 4;
    int*   bucketCount  = (int*)w;                   w += (size_t)NCNT * 4;
    int*   bucketOffset = (int*)w;                   w += (size_t)(NCNT + 4) * 4;
    int*   gCur   = (int*)w;                         w += (size_t)NCNT * 4;
    // bpair (16 MB, dead after csr_finalize) and egoC (19.2 MB, born at
    // layer-2 gather) share the tail region: lifetimes don't overlap.
    u64*   bpair  = (u64*)w;
    ushort* egoC  = (ushort*)w;

    const int T = 256;
    const int EW_BLOCKS = 2048;
    const int GATHER_BLOCKS = (N_NODES + 7) / 8;     // 18750

    lgcn_init<<<EW_BLOCKS, T, 0, stream>>>(
        (const float4*)user_emb, (const float4*)item_emb, (uint2*)egoA);

    zero_ints<<<NCNT / T, T, 0, stream>>>(bucketCount, NCNT);
    bucket_hist<<<NTILE, BT, 0, stream>>>(edge_src, bucketCount);
    bucket_scan<<<1, 1024, 0, stream>>>(bucketCount, bucketOffset, gCur, rowPtr);
    bucket_scatter<<<NTILE, BT, 0, stream>>>(edge_src, edge_dst, edge_norm,
                                             gCur, bpair);
    csr_finalize<<<NBUCKET, 1024, 0, stream>>>(bucketOffset, bpair,
                                               rowPtr, pairs);

    // Layer 1: ego0(A) -> ego1(B)             (nego only)
    lgcn_gather<<<GATHER_BLOCKS, T, 0, stream>>>(egoA, egoB, acc,
                                                 (const ushort*)0, (const ushort*)0,
                                                 rowPtr, pairs, 0);
    // Layer 2: ego1(B) -> ego2(C)             (nego only)
    lgcn_gather<<<GATHER_BLOCKS, T, 0, stream>>>(egoB, egoC, acc,
                                                 (const ushort*)0, (const ushort*)0,
                                                 rowPtr, pairs, 0);
    // Layer 3: ego2(C) -> s; acc = (A + B + C + s) / 4
    lgcn_gather<<<GATHER_BLOCKS, T, 0, stream>>>(egoC, (ushort*)0, acc,
                                                 egoA, egoB,
                                                 rowPtr, pairs, 1);
}